// Round 5
// baseline (207.410 us; speedup 1.0000x reference)
//
#include <hip/hip_runtime.h>
#include <stdint.h>

#define IN_F   4096
#define R_DIM  128
#define OUT_D  4096
#define BSZ    8
#define SEQ    2048
#define M1     (BSZ * SEQ)   /* 16384 */
#define SCALE  2.0f

typedef __attribute__((ext_vector_type(8))) short short8;
typedef __attribute__((ext_vector_type(4))) float f32x4;

static __device__ __forceinline__ unsigned short bf16_1(float f) {
    union { __bf16 h; unsigned short u; } v; v.h = (__bf16)f; return v.u;
}
static __device__ __forceinline__ uint32_t pack2(float a, float b) {
    union { __bf16 h[2]; uint32_t u; } v;
    v.h[0] = (__bf16)a; v.h[1] = (__bf16)b;
    return v.u;
}
static __device__ __forceinline__ float bf16_to_f32(unsigned short h) {
    union { uint32_t u; float f; } v; v.u = ((uint32_t)h) << 16;
    return v.f;
}
static __device__ __forceinline__ int swz16(int r) { return ((r >> 2) ^ r) & 15; }

// ================= k_prep: Wd f32 -> bf16 MFMA B-fragment layout =================
// Wfrag[((T*8 + c)*128 + col)*8 + e] = bf16(Wd[col][T*64 + kki*32 + g*8 + e]), c = kki*4+g
__global__ __launch_bounds__(256) void k_prep(const float* __restrict__ Wd,
                                              unsigned short* __restrict__ Wfrag) {
    const int gid = blockIdx.x * 256 + threadIdx.x;   // 0..65535
    const int T   = gid >> 10;
    const int c   = (gid >> 7) & 7;
    const int col = gid & 127;
    const int kki = c >> 2, g = c & 3;
    const int k0  = T * 64 + kki * 32 + g * 8;
    const float* src = Wd + (size_t)col * IN_F + k0;
    float4 v0 = *(const float4*)(src);
    float4 v1 = *(const float4*)(src + 4);
    uint4 q;
    q.x = pack2(v0.x, v0.y); q.y = pack2(v0.z, v0.w);
    q.z = pack2(v1.x, v1.y); q.w = pack2(v1.z, v1.w);
    *(uint4*)(Wfrag + (size_t)gid * 8) = q;
}

// ================= Pass 1 v4: barrier-free, LDS-free =================
struct AF { float4 a0, a1, a2, a3; };

static __device__ __forceinline__ AF load_A(const float* p) {
    AF r;
    r.a0 = *(const float4*)(p);
    r.a1 = *(const float4*)(p + 4);
    r.a2 = *(const float4*)(p + 32);
    r.a3 = *(const float4*)(p + 36);
    return r;
}
static __device__ __forceinline__ void cvt_A(const AF& a, short8& f0, short8& f1) {
    uint32_t* u0 = (uint32_t*)&f0;
    uint32_t* u1 = (uint32_t*)&f1;
    u0[0] = pack2(a.a0.x, a.a0.y); u0[1] = pack2(a.a0.z, a.a0.w);
    u0[2] = pack2(a.a1.x, a.a1.y); u0[3] = pack2(a.a1.z, a.a1.w);
    u1[0] = pack2(a.a2.x, a.a2.y); u1[1] = pack2(a.a2.z, a.a2.w);
    u1[2] = pack2(a.a3.x, a.a3.y); u1[3] = pack2(a.a3.z, a.a3.w);
}

template <int KSPLIT>
__global__ __launch_bounds__(256, 6) void k_down_v4(const float* __restrict__ x,
                                                    const unsigned short* __restrict__ Wfrag,
                                                    unsigned short* __restrict__ part) {
    constexpr int KCHUNK = IN_F / KSPLIT;
    constexpr int NT     = KCHUNK / 64;

    const int tid  = threadIdx.x;
    const int lane = tid & 63;
    const int w    = tid >> 6;                 // 0..3
    const int mt   = blockIdx.x & 255;         // 256 m-tiles of 64 rows
    const int ks   = blockIdx.x >> 8;          // 0..KSPLIT-1
    const int kbeg = ks * KCHUNK;

    f32x4 acc[8];
#pragma unroll
    for (int nf = 0; nf < 8; ++nf)
#pragma unroll
        for (int j = 0; j < 4; ++j) acc[nf][j] = 0.0f;

    const int row = mt * 64 + w * 16 + (lane & 15);
    const float* asrc = x + (size_t)row * IN_F + kbeg + (lane >> 4) * 8;
    // per-lane B base: k-chunk block for this K-range + lane's (g,col) offset
    const unsigned short* bbase = Wfrag + ((size_t)(kbeg / 64) * 1024 +
                                           (size_t)((lane >> 4) * 128 + (lane & 15))) * 8;

    AF a_nxt = load_A(asrc);

    for (int t = 0; t < NT; ++t) {
        AF a_cur = a_nxt;
        if (t + 1 < NT) a_nxt = load_A(asrc + (size_t)(t + 1) * 64);
        short8 af0, af1;
        cvt_A(a_cur, af0, af1);
        const unsigned short* bt = bbase + (size_t)t * 8192;
#pragma unroll
        for (int kki = 0; kki < 2; ++kki) {
            const short8 af = kki ? af1 : af0;
#pragma unroll
            for (int nf = 0; nf < 8; ++nf) {
                const short8 bf = *(const short8*)(bt + kki * 4096 + nf * 128);
                acc[nf] = __builtin_amdgcn_mfma_f32_16x16x32_bf16(af, bf, acc[nf], 0, 0, 0);
            }
        }
    }

    unsigned short* dst = part + (size_t)ks * M1 * R_DIM;
    const int orow = mt * 64 + w * 16 + ((lane >> 4) << 2);
    const int ocol = lane & 15;
#pragma unroll
    for (int nf = 0; nf < 8; ++nf)
#pragma unroll
        for (int j = 0; j < 4; ++j)
            dst[(size_t)(orow + j) * R_DIM + nf * 16 + ocol] = bf16_1(acc[nf][j]);
}

// ---------------- Reduce: down = sum_ks part[ks] (bf16) ----------------
template <int KSPLIT>
__global__ __launch_bounds__(512) void k_reduce(const unsigned short* __restrict__ part,
                                                unsigned short* __restrict__ down) {
    const size_t chunk = (size_t)blockIdx.x * 512 + threadIdx.x;
    const size_t off = chunk * 8;
    if (off >= (size_t)M1 * R_DIM) return;
    float lo[4] = {0, 0, 0, 0}, hi[4] = {0, 0, 0, 0};
#pragma unroll
    for (int p = 0; p < KSPLIT; ++p) {
        uint4 q = *(const uint4*)(part + (size_t)p * M1 * R_DIM + off);
        const uint32_t* a = (const uint32_t*)&q;
#pragma unroll
        for (int i = 0; i < 4; ++i) {
            lo[i] += bf16_to_f32((unsigned short)(a[i] & 0xFFFF));
            hi[i] += bf16_to_f32((unsigned short)(a[i] >> 16));
        }
    }
    uint4 r;
    uint32_t* o = (uint32_t*)&r;
#pragma unroll
    for (int i = 0; i < 4; ++i) o[i] = pack2(lo[i], hi[i]);
    *(uint4*)(down + off) = r;
}

// ---------------- Fallback pass 1 (no split; only if ws too small) ----------------
#define BM1 64
#define BK1 64
#define PAD 8
static __device__ __forceinline__ void st_bf16x4(unsigned short* p, float4 v) {
    uint2 q; q.x = pack2(v.x, v.y); q.y = pack2(v.z, v.w);
    *(uint2*)p = q;
}

__global__ __launch_bounds__(512) void k_down(const float* __restrict__ x,
                                              const float* __restrict__ Wd,
                                              unsigned short* __restrict__ down) {
    __shared__ unsigned short As[BM1][BK1 + PAD];
    __shared__ unsigned short Bsh[R_DIM][BK1 + PAD];

    const int tid  = threadIdx.x;
    const int lane = tid & 63;
    const int w    = tid >> 6;
    const int wm   = w >> 2;
    const int wn   = w & 3;
    const int row0 = blockIdx.x * BM1;

    f32x4 acc[2][2];
#pragma unroll
    for (int m = 0; m < 2; ++m)
#pragma unroll
        for (int n = 0; n < 2; ++n)
#pragma unroll
            for (int j = 0; j < 4; ++j) acc[m][n][j] = 0.0f;

    const int arow = tid >> 4;
    const int acol = (tid & 15) << 2;
    float4 ra[2], rb[4];

    ra[0] = *(const float4*)(x + (size_t)(row0 + arow) * IN_F + acol);
    ra[1] = *(const float4*)(x + (size_t)(row0 + arow + 32) * IN_F + acol);
#pragma unroll
    for (int i = 0; i < 4; ++i)
        rb[i] = *(const float4*)(Wd + (size_t)(arow + 32 * i) * IN_F + acol);
    st_bf16x4(&As[arow][acol], ra[0]);
    st_bf16x4(&As[arow + 32][acol], ra[1]);
#pragma unroll
    for (int i = 0; i < 4; ++i) st_bf16x4(&Bsh[arow + 32 * i][acol], rb[i]);
    __syncthreads();

    for (int k0 = BK1; k0 <= IN_F; k0 += BK1) {
        const bool more = (k0 < IN_F);
        if (more) {
            ra[0] = *(const float4*)(x + (size_t)(row0 + arow) * IN_F + k0 + acol);
            ra[1] = *(const float4*)(x + (size_t)(row0 + arow + 32) * IN_F + k0 + acol);
#pragma unroll
            for (int i = 0; i < 4; ++i)
                rb[i] = *(const float4*)(Wd + (size_t)(arow + 32 * i) * IN_F + k0 + acol);
        }
#pragma unroll
        for (int kk = 0; kk < BK1; kk += 32) {
            short8 af[2], bfv[2];
#pragma unroll
            for (int m = 0; m < 2; ++m)
                af[m] = *(const short8*)&As[wm * 32 + m * 16 + (lane & 15)][kk + (lane >> 4) * 8];
#pragma unroll
            for (int n = 0; n < 2; ++n)
                bfv[n] = *(const short8*)&Bsh[wn * 32 + n * 16 + (lane & 15)][kk + (lane >> 4) * 8];
#pragma unroll
            for (int m = 0; m < 2; ++m)
#pragma unroll
                for (int n = 0; n < 2; ++n)
                    acc[m][n] = __builtin_amdgcn_mfma_f32_16x16x32_bf16(af[m], bfv[n], acc[m][n], 0, 0, 0);
        }
        __syncthreads();
        if (more) {
            st_bf16x4(&As[arow][acol], ra[0]);
            st_bf16x4(&As[arow + 32][acol], ra[1]);
#pragma unroll
            for (int i = 0; i < 4; ++i) st_bf16x4(&Bsh[arow + 32 * i][acol], rb[i]);
            __syncthreads();
        }
    }

#pragma unroll
    for (int m = 0; m < 2; ++m)
#pragma unroll
        for (int n = 0; n < 2; ++n)
#pragma unroll
            for (int j = 0; j < 4; ++j) {
                int r = row0 + wm * 32 + m * 16 + ((lane >> 4) << 2) + j;
                int c = wn * 32 + n * 16 + (lane & 15);
                down[(size_t)r * R_DIM + c] = bf16_1(acc[m][n][j]);
            }
}

// ---------------- Pass 2: out[b][2048][4096] = down[b] @ graph_rep[b] * SCALE ----------------
#define BM2 64
#define BN2 128

__global__ __launch_bounds__(512) void k_out(const unsigned short* __restrict__ down,
                                             const float* __restrict__ g,
                                             float* __restrict__ out) {
    __shared__ unsigned short As[BM2 * R_DIM];
    __shared__ unsigned short Bsv[BN2 * R_DIM];

    const int tid  = threadIdx.x;
    const int lane = tid & 63;
    const int w    = tid >> 6;
    const int wm   = w >> 2;
    const int wn   = w & 3;
    const int blk  = blockIdx.x;
    const int o_t  = blk & 31;
    const int s_t  = (blk >> 5) & 31;
    const int b    = blk >> 10;
    const int s0   = s_t * BM2;
    const int o0   = o_t * BN2;

    {
        const int rr = tid >> 4;
        const int j  = tid & 15;
        const int sl0 = j ^ swz16(rr);
        const int sl1 = j ^ swz16(rr + 32);
        *(uint4*)&As[rr * R_DIM + sl0 * 8] =
            *(const uint4*)(down + ((size_t)(b * SEQ + s0 + rr) * R_DIM) + j * 8);
        *(uint4*)&As[(rr + 32) * R_DIM + sl1 * 8] =
            *(const uint4*)(down + ((size_t)(b * SEQ + s0 + rr + 32) * R_DIM) + j * 8);
    }
    {
        const int oq  = tid & 31;
        const int kq0 = tid >> 5;
#pragma unroll
        for (int rep = 0; rep < 2; ++rep) {
            const int kq = kq0 + 16 * rep;
            float4 v0 = *(const float4*)(g + ((size_t)b * R_DIM + 4 * kq + 0) * OUT_D + o0 + 4 * oq);
            float4 v1 = *(const float4*)(g + ((size_t)b * R_DIM + 4 * kq + 1) * OUT_D + o0 + 4 * oq);
            float4 v2 = *(const float4*)(g + ((size_t)b * R_DIM + 4 * kq + 2) * OUT_D + o0 + 4 * oq);
            float4 v3 = *(const float4*)(g + ((size_t)b * R_DIM + 4 * kq + 3) * OUT_D + o0 + 4 * oq);
            const float* p0 = (const float*)&v0;
            const float* p1 = (const float*)&v1;
            const float* p2 = (const float*)&v2;
            const float* p3 = (const float*)&v3;
#pragma unroll
            for (int i = 0; i < 4; ++i) {
                const int o = 4 * oq + i;
                uint2 q;
                q.x = pack2(p0[i], p1[i]);
                q.y = pack2(p2[i], p3[i]);
                const int slot = (kq >> 1) ^ swz16(o);
                *(uint2*)&Bsv[o * R_DIM + slot * 8 + (kq & 1) * 4] = q;
            }
        }
    }
    __syncthreads();

    f32x4 acc[2][2];
#pragma unroll
    for (int m = 0; m < 2; ++m)
#pragma unroll
        for (int n = 0; n < 2; ++n)
#pragma unroll
            for (int j = 0; j < 4; ++j) acc[m][n][j] = 0.0f;

#pragma unroll
    for (int kk = 0; kk < R_DIM; kk += 32) {
        const int cbase = (kk >> 3) + (lane >> 4);
        short8 af[2], bfv[2];
#pragma unroll
        for (int m = 0; m < 2; ++m) {
            const int r = wm * 32 + m * 16 + (lane & 15);
            af[m] = *(const short8*)&As[r * R_DIM + (cbase ^ swz16(r)) * 8];
        }
#pragma unroll
        for (int n = 0; n < 2; ++n) {
            const int o = wn * 32 + n * 16 + (lane & 15);
            bfv[n] = *(const short8*)&Bsv[o * R_DIM + (cbase ^ swz16(o)) * 8];
        }
#pragma unroll
        for (int m = 0; m < 2; ++m)
#pragma unroll
            for (int n = 0; n < 2; ++n)
                acc[m][n] = __builtin_amdgcn_mfma_f32_16x16x32_bf16(af[m], bfv[n], acc[m][n], 0, 0, 0);
    }

#pragma unroll
    for (int m = 0; m < 2; ++m)
#pragma unroll
        for (int n = 0; n < 2; ++n)
#pragma unroll
            for (int j = 0; j < 4; ++j) {
                int s = s0 + wm * 32 + m * 16 + ((lane >> 4) << 2) + j;
                int o = o0 + wn * 32 + n * 16 + (lane & 15);
                out[((size_t)b * SEQ + s) * OUT_D + o] = SCALE * acc[m][n][j];
            }
}

extern "C" void kernel_launch(void* const* d_in, const int* in_sizes, int n_in,
                              void* d_out, int out_size, void* d_ws, size_t ws_size,
                              hipStream_t stream) {
    const float* graph_rep = (const float*)d_in[0];
    const float* x         = (const float*)d_in[1];
    const float* Wd        = (const float*)d_in[2];
    float* out             = (float*)d_out;

    const size_t de = (size_t)M1 * R_DIM;   // down elems (2M)
    const size_t need8 = (8 + 1) * de * sizeof(unsigned short);   // 36 MB
    const size_t need4 = (4 + 1) * de * sizeof(unsigned short);   // 20 MB
    const int out_grid = BSZ * (SEQ / BM2) * (OUT_D / BN2);

    if (ws_size >= need8) {
        unsigned short* part  = (unsigned short*)d_ws;
        unsigned short* down  = part + 8 * de;
        unsigned short* wfrag = down;   // alias: Wfrag used before down is written
        k_prep<<<256, 256, 0, stream>>>(Wd, wfrag);
        k_down_v4<8><<<256 * 8, 256, 0, stream>>>(x, wfrag, part);
        k_reduce<8><<<(int)(de / 8 / 512), 512, 0, stream>>>(part, down);
        k_out<<<out_grid, 512, 0, stream>>>(down, graph_rep, out);
    } else if (ws_size >= need4) {
        unsigned short* part  = (unsigned short*)d_ws;
        unsigned short* down  = part + 4 * de;
        unsigned short* wfrag = down;
        k_prep<<<256, 256, 0, stream>>>(Wd, wfrag);
        k_down_v4<4><<<256 * 4, 256, 0, stream>>>(x, wfrag, part);
        k_reduce<4><<<(int)(de / 8 / 512), 512, 0, stream>>>(part, down);
        k_out<<<out_grid, 512, 0, stream>>>(down, graph_rep, out);
    } else {
        unsigned short* down = (unsigned short*)d_ws;
        k_down<<<M1 / BM1, 512, 0, stream>>>(x, Wd, down);
        k_out<<<out_grid, 512, 0, stream>>>(down, graph_rep, out);
    }
}

// Round 6
// 176.319 us; speedup vs baseline: 1.1763x; 1.1763x over previous
//
#include <hip/hip_runtime.h>
#include <stdint.h>

#define IN_F   4096
#define R_DIM  128
#define OUT_D  4096
#define BSZ    8
#define SEQ    2048
#define M1     (BSZ * SEQ)   /* 16384 */
#define SCALE  2.0f

typedef __attribute__((ext_vector_type(8))) short short8;
typedef __attribute__((ext_vector_type(4))) float f32x4;

static __device__ __forceinline__ unsigned short bf16_1(float f) {
    union { __bf16 h; unsigned short u; } v; v.h = (__bf16)f; return v.u;
}
static __device__ __forceinline__ uint32_t pack2(float a, float b) {
    union { __bf16 h[2]; uint32_t u; } v;
    v.h[0] = (__bf16)a; v.h[1] = (__bf16)b;
    return v.u;
}
static __device__ __forceinline__ float bf16_to_f32(unsigned short h) {
    union { uint32_t u; float f; } v; v.u = ((uint32_t)h) << 16;
    return v.f;
}
static __device__ __forceinline__ int swz16(int r) { return ((r >> 2) ^ r) & 15; }

static __device__ __forceinline__ void gll16(const void* g, void* l) {
    __builtin_amdgcn_global_load_lds(
        (const __attribute__((address_space(1))) void*)g,
        (__attribute__((address_space(3))) void*)l, 16, 0, 0);
}

// ================= k_prep_w: Wd f32 -> bf16 row-major copy =================
__global__ __launch_bounds__(256) void k_prep_w(const float* __restrict__ Wd,
                                                unsigned short* __restrict__ wdbf) {
    const int gid = blockIdx.x * 256 + threadIdx.x;   // x8 elems, 512K total
    const float4 v0 = *(const float4*)(Wd + (size_t)gid * 8);
    const float4 v1 = *(const float4*)(Wd + (size_t)gid * 8 + 4);
    uint4 q;
    q.x = pack2(v0.x, v0.y); q.y = pack2(v0.z, v0.w);
    q.z = pack2(v1.x, v1.y); q.w = pack2(v1.z, v1.w);
    *(uint4*)(wdbf + (size_t)gid * 8) = q;
}

// ================= Pass 1 v5: A reg-staged, B global_load_lds, dbuf, 1 barrier/step =================
template <int KSPLIT>
__global__ __launch_bounds__(512, 6) void k_down_v5(const float* __restrict__ x,
                                                    const unsigned short* __restrict__ wdbf,
                                                    unsigned short* __restrict__ part) {
    constexpr int KCHUNK = IN_F / KSPLIT;
    constexpr int NT     = KCHUNK / 64;

    __shared__ unsigned short As[2][64][72];       // bf16, +8 pad (2-way, free)
    __shared__ unsigned short Bs[2][R_DIM * 64];   // bf16, linear; src-preswizzled chunks

    const int tid  = threadIdx.x;
    const int lane = tid & 63;
    const int w    = tid >> 6;
    const int wm   = w >> 2;   // 0..1
    const int wn   = w & 3;    // 0..3
    const int mt   = blockIdx.x & 255;
    const int ks   = blockIdx.x >> 8;
    const int row0 = mt * 64;
    const int kbeg = ks * KCHUNK;

    f32x4 acc[2][2];
#pragma unroll
    for (int m = 0; m < 2; ++m)
#pragma unroll
        for (int n = 0; n < 2; ++n)
#pragma unroll
            for (int j = 0; j < 4; ++j) acc[m][n][j] = 0.0f;

    // A: thread -> row = tid>>3 (0..63), col8 = (tid&7)*8 ; 8 f32 -> 1 ds_write_b128
    const int arow = tid >> 3;
    const int acol = (tid & 7) << 3;
    const float* asrc = x + (size_t)(row0 + arow) * IN_F + kbeg + acol;

    // B: thread -> slot tid (r=tid>>3, s=tid&7) and tid+512 (r+64); src chunk = s ^ (r&7)
    const int brow = tid >> 3;
    const int bs_s = tid & 7;
    const int bchunk = bs_s ^ (brow & 7);   // same for brow and brow+64
    const unsigned short* bsrc0 = wdbf + (size_t)brow * IN_F + kbeg + bchunk * 8;
    const unsigned short* bsrc1 = wdbf + (size_t)(brow + 64) * IN_F + kbeg + bchunk * 8;

    float4 ra0, ra1;

    // prologue: stage tile 0
    gll16(bsrc0, &Bs[0][tid * 8]);
    gll16(bsrc1, &Bs[0][(tid + 512) * 8]);
    ra0 = *(const float4*)(asrc);
    ra1 = *(const float4*)(asrc + 4);
    {
        uint4 q;
        q.x = pack2(ra0.x, ra0.y); q.y = pack2(ra0.z, ra0.w);
        q.z = pack2(ra1.x, ra1.y); q.w = pack2(ra1.z, ra1.w);
        *(uint4*)&As[0][arow][acol] = q;
    }
    __syncthreads();

    for (int t = 0; t < NT; ++t) {
        const int cur = t & 1, nxt = cur ^ 1;
        if (t + 1 < NT) {
            gll16(bsrc0 + (t + 1) * 64, &Bs[nxt][tid * 8]);
            gll16(bsrc1 + (t + 1) * 64, &Bs[nxt][(tid + 512) * 8]);
            ra0 = *(const float4*)(asrc + (t + 1) * 64);
            ra1 = *(const float4*)(asrc + (t + 1) * 64 + 4);
        }
        // compute tile t
#pragma unroll
        for (int kk = 0; kk < 64; kk += 32) {
            const int g = lane >> 4;                  // 0..3
            const int c = (kk >> 3) + g;              // 16B chunk index 0..7
            short8 af[2], bfv[2];
#pragma unroll
            for (int m = 0; m < 2; ++m) {
                const int r = wm * 32 + m * 16 + (lane & 15);
                af[m] = *(const short8*)&As[cur][r][kk + g * 8];
            }
#pragma unroll
            for (int n = 0; n < 2; ++n) {
                const int rB = wn * 32 + n * 16 + (lane & 15);
                const int slot = c ^ (rB & 7);
                bfv[n] = *(const short8*)&Bs[cur][rB * 64 + slot * 8];
            }
#pragma unroll
            for (int m = 0; m < 2; ++m)
#pragma unroll
                for (int n = 0; n < 2; ++n)
                    acc[m][n] = __builtin_amdgcn_mfma_f32_16x16x32_bf16(af[m], bfv[n], acc[m][n], 0, 0, 0);
        }
        if (t + 1 < NT) {
            uint4 q;
            q.x = pack2(ra0.x, ra0.y); q.y = pack2(ra0.z, ra0.w);
            q.z = pack2(ra1.x, ra1.y); q.w = pack2(ra1.z, ra1.w);
            *(uint4*)&As[nxt][arow][acol] = q;
        }
        __syncthreads();
    }

    unsigned short* dst = part + (size_t)ks * M1 * R_DIM;
#pragma unroll
    for (int m = 0; m < 2; ++m)
#pragma unroll
        for (int n = 0; n < 2; ++n)
#pragma unroll
            for (int j = 0; j < 4; ++j) {
                int r = row0 + wm * 32 + m * 16 + ((lane >> 4) << 2) + j;
                int c = wn * 32 + n * 16 + (lane & 15);
                dst[(size_t)r * R_DIM + c] = bf16_1(acc[m][n][j]);
            }
}

// ---------------- Reduce: down = sum_ks part[ks] (bf16) ----------------
template <int KSPLIT>
__global__ __launch_bounds__(512) void k_reduce(const unsigned short* __restrict__ part,
                                                unsigned short* __restrict__ down) {
    const size_t chunk = (size_t)blockIdx.x * 512 + threadIdx.x;
    const size_t off = chunk * 8;
    if (off >= (size_t)M1 * R_DIM) return;
    float lo[4] = {0, 0, 0, 0}, hi[4] = {0, 0, 0, 0};
#pragma unroll
    for (int p = 0; p < KSPLIT; ++p) {
        uint4 q = *(const uint4*)(part + (size_t)p * M1 * R_DIM + off);
        const uint32_t* a = (const uint32_t*)&q;
#pragma unroll
        for (int i = 0; i < 4; ++i) {
            lo[i] += bf16_to_f32((unsigned short)(a[i] & 0xFFFF));
            hi[i] += bf16_to_f32((unsigned short)(a[i] >> 16));
        }
    }
    uint4 r;
    uint32_t* o = (uint32_t*)&r;
#pragma unroll
    for (int i = 0; i < 4; ++i) o[i] = pack2(lo[i], hi[i]);
    *(uint4*)(down + off) = r;
}

// ---------------- Fallback pass 1 (no split; only if ws too small) ----------------
#define BM1 64
#define BK1 64
#define PAD 8
static __device__ __forceinline__ void st_bf16x4(unsigned short* p, float4 v) {
    uint2 q; q.x = pack2(v.x, v.y); q.y = pack2(v.z, v.w);
    *(uint2*)p = q;
}

__global__ __launch_bounds__(512) void k_down(const float* __restrict__ x,
                                              const float* __restrict__ Wd,
                                              unsigned short* __restrict__ down) {
    __shared__ unsigned short As[BM1][BK1 + PAD];
    __shared__ unsigned short Bsh[R_DIM][BK1 + PAD];

    const int tid  = threadIdx.x;
    const int lane = tid & 63;
    const int w    = tid >> 6;
    const int wm   = w >> 2;
    const int wn   = w & 3;
    const int row0 = blockIdx.x * BM1;

    f32x4 acc[2][2];
#pragma unroll
    for (int m = 0; m < 2; ++m)
#pragma unroll
        for (int n = 0; n < 2; ++n)
#pragma unroll
            for (int j = 0; j < 4; ++j) acc[m][n][j] = 0.0f;

    const int arow = tid >> 4;
    const int acol = (tid & 15) << 2;
    float4 ra[2], rb[4];

    ra[0] = *(const float4*)(x + (size_t)(row0 + arow) * IN_F + acol);
    ra[1] = *(const float4*)(x + (size_t)(row0 + arow + 32) * IN_F + acol);
#pragma unroll
    for (int i = 0; i < 4; ++i)
        rb[i] = *(const float4*)(Wd + (size_t)(arow + 32 * i) * IN_F + acol);
    st_bf16x4(&As[arow][acol], ra[0]);
    st_bf16x4(&As[arow + 32][acol], ra[1]);
#pragma unroll
    for (int i = 0; i < 4; ++i) st_bf16x4(&Bsh[arow + 32 * i][acol], rb[i]);
    __syncthreads();

    for (int k0 = BK1; k0 <= IN_F; k0 += BK1) {
        const bool more = (k0 < IN_F);
        if (more) {
            ra[0] = *(const float4*)(x + (size_t)(row0 + arow) * IN_F + k0 + acol);
            ra[1] = *(const float4*)(x + (size_t)(row0 + arow + 32) * IN_F + k0 + acol);
#pragma unroll
            for (int i = 0; i < 4; ++i)
                rb[i] = *(const float4*)(Wd + (size_t)(arow + 32 * i) * IN_F + k0 + acol);
        }
#pragma unroll
        for (int kk = 0; kk < BK1; kk += 32) {
            short8 af[2], bfv[2];
#pragma unroll
            for (int m = 0; m < 2; ++m)
                af[m] = *(const short8*)&As[wm * 32 + m * 16 + (lane & 15)][kk + (lane >> 4) * 8];
#pragma unroll
            for (int n = 0; n < 2; ++n)
                bfv[n] = *(const short8*)&Bsh[wn * 32 + n * 16 + (lane & 15)][kk + (lane >> 4) * 8];
#pragma unroll
            for (int m = 0; m < 2; ++m)
#pragma unroll
                for (int n = 0; n < 2; ++n)
                    acc[m][n] = __builtin_amdgcn_mfma_f32_16x16x32_bf16(af[m], bfv[n], acc[m][n], 0, 0, 0);
        }
        __syncthreads();
        if (more) {
            st_bf16x4(&As[arow][acol], ra[0]);
            st_bf16x4(&As[arow + 32][acol], ra[1]);
#pragma unroll
            for (int i = 0; i < 4; ++i) st_bf16x4(&Bsh[arow + 32 * i][acol], rb[i]);
            __syncthreads();
        }
    }

#pragma unroll
    for (int m = 0; m < 2; ++m)
#pragma unroll
        for (int n = 0; n < 2; ++n)
#pragma unroll
            for (int j = 0; j < 4; ++j) {
                int r = row0 + wm * 32 + m * 16 + ((lane >> 4) << 2) + j;
                int c = wn * 32 + n * 16 + (lane & 15);
                down[(size_t)r * R_DIM + c] = bf16_1(acc[m][n][j]);
            }
}

// ---------------- Pass 2: out[b][2048][4096] = down[b] @ graph_rep[b] * SCALE ----------------
#define BM2 64
#define BN2 128

__global__ __launch_bounds__(512) void k_out(const unsigned short* __restrict__ down,
                                             const float* __restrict__ g,
                                             float* __restrict__ out) {
    __shared__ unsigned short As[BM2 * R_DIM];
    __shared__ unsigned short Bsv[BN2 * R_DIM];

    const int tid  = threadIdx.x;
    const int lane = tid & 63;
    const int w    = tid >> 6;
    const int wm   = w >> 2;
    const int wn   = w & 3;
    const int blk  = blockIdx.x;
    const int o_t  = blk & 31;
    const int s_t  = (blk >> 5) & 31;
    const int b    = blk >> 10;
    const int s0   = s_t * BM2;
    const int o0   = o_t * BN2;

    {
        const int rr = tid >> 4;
        const int j  = tid & 15;
        const int sl0 = j ^ swz16(rr);
        const int sl1 = j ^ swz16(rr + 32);
        *(uint4*)&As[rr * R_DIM + sl0 * 8] =
            *(const uint4*)(down + ((size_t)(b * SEQ + s0 + rr) * R_DIM) + j * 8);
        *(uint4*)&As[(rr + 32) * R_DIM + sl1 * 8] =
            *(const uint4*)(down + ((size_t)(b * SEQ + s0 + rr + 32) * R_DIM) + j * 8);
    }
    {
        const int oq  = tid & 31;
        const int kq0 = tid >> 5;
#pragma unroll
        for (int rep = 0; rep < 2; ++rep) {
            const int kq = kq0 + 16 * rep;
            float4 v0 = *(const float4*)(g + ((size_t)b * R_DIM + 4 * kq + 0) * OUT_D + o0 + 4 * oq);
            float4 v1 = *(const float4*)(g + ((size_t)b * R_DIM + 4 * kq + 1) * OUT_D + o0 + 4 * oq);
            float4 v2 = *(const float4*)(g + ((size_t)b * R_DIM + 4 * kq + 2) * OUT_D + o0 + 4 * oq);
            float4 v3 = *(const float4*)(g + ((size_t)b * R_DIM + 4 * kq + 3) * OUT_D + o0 + 4 * oq);
            const float* p0 = (const float*)&v0;
            const float* p1 = (const float*)&v1;
            const float* p2 = (const float*)&v2;
            const float* p3 = (const float*)&v3;
#pragma unroll
            for (int i = 0; i < 4; ++i) {
                const int o = 4 * oq + i;
                uint2 q;
                q.x = pack2(p0[i], p1[i]);
                q.y = pack2(p2[i], p3[i]);
                const int slot = (kq >> 1) ^ swz16(o);
                *(uint2*)&Bsv[o * R_DIM + slot * 8 + (kq & 1) * 4] = q;
            }
        }
    }
    __syncthreads();

    f32x4 acc[2][2];
#pragma unroll
    for (int m = 0; m < 2; ++m)
#pragma unroll
        for (int n = 0; n < 2; ++n)
#pragma unroll
            for (int j = 0; j < 4; ++j) acc[m][n][j] = 0.0f;

#pragma unroll
    for (int kk = 0; kk < R_DIM; kk += 32) {
        const int cbase = (kk >> 3) + (lane >> 4);
        short8 af[2], bfv[2];
#pragma unroll
        for (int m = 0; m < 2; ++m) {
            const int r = wm * 32 + m * 16 + (lane & 15);
            af[m] = *(const short8*)&As[r * R_DIM + (cbase ^ swz16(r)) * 8];
        }
#pragma unroll
        for (int n = 0; n < 2; ++n) {
            const int o = wn * 32 + n * 16 + (lane & 15);
            bfv[n] = *(const short8*)&Bsv[o * R_DIM + (cbase ^ swz16(o)) * 8];
        }
#pragma unroll
        for (int m = 0; m < 2; ++m)
#pragma unroll
            for (int n = 0; n < 2; ++n)
                acc[m][n] = __builtin_amdgcn_mfma_f32_16x16x32_bf16(af[m], bfv[n], acc[m][n], 0, 0, 0);
    }

#pragma unroll
    for (int m = 0; m < 2; ++m)
#pragma unroll
        for (int n = 0; n < 2; ++n)
#pragma unroll
            for (int j = 0; j < 4; ++j) {
                int s = s0 + wm * 32 + m * 16 + ((lane >> 4) << 2) + j;
                int o = o0 + wn * 32 + n * 16 + (lane & 15);
                out[((size_t)b * SEQ + s) * OUT_D + o] = SCALE * acc[m][n][j];
            }
}

extern "C" void kernel_launch(void* const* d_in, const int* in_sizes, int n_in,
                              void* d_out, int out_size, void* d_ws, size_t ws_size,
                              hipStream_t stream) {
    const float* graph_rep = (const float*)d_in[0];
    const float* x         = (const float*)d_in[1];
    const float* Wd        = (const float*)d_in[2];
    float* out             = (float*)d_out;

    const size_t de = (size_t)M1 * R_DIM;               // 2M elems
    const size_t we = (size_t)R_DIM * IN_F;             // 512K elems
    const size_t need8 = (9 * de + we) * sizeof(unsigned short);   // ~37 MB
    const size_t need4 = (5 * de + we) * sizeof(unsigned short);   // ~21 MB
    const int out_grid = BSZ * (SEQ / BM2) * (OUT_D / BN2);

    if (ws_size >= need8) {
        unsigned short* part = (unsigned short*)d_ws;
        unsigned short* down = part + 8 * de;
        unsigned short* wdbf = part + 9 * de;
        k_prep_w<<<256, 256, 0, stream>>>(Wd, wdbf);
        k_down_v5<8><<<256 * 8, 512, 0, stream>>>(x, wdbf, part);
        k_reduce<8><<<(int)(de / 8 / 512), 512, 0, stream>>>(part, down);
        k_out<<<out_grid, 512, 0, stream>>>(down, graph_rep, out);
    } else if (ws_size >= need4) {
        unsigned short* part = (unsigned short*)d_ws;
        unsigned short* down = part + 4 * de;
        unsigned short* wdbf = part + 5 * de;
        k_prep_w<<<256, 256, 0, stream>>>(Wd, wdbf);
        k_down_v5<4><<<256 * 4, 512, 0, stream>>>(x, wdbf, part);
        k_reduce<4><<<(int)(de / 8 / 512), 512, 0, stream>>>(part, down);
        k_out<<<out_grid, 512, 0, stream>>>(down, graph_rep, out);
    } else {
        unsigned short* down = (unsigned short*)d_ws;
        k_down<<<M1 / BM1, 512, 0, stream>>>(x, Wd, down);
        k_out<<<out_grid, 512, 0, stream>>>(down, graph_rep, out);
    }
}